// Round 1
// baseline (11479.631 us; speedup 1.0000x reference)
//
#include <hip/hip_runtime.h>

#define D 256   // feature width for both aggregation stages (D_IN == D_HID == 256)

// ---------------------------------------------------------------------------
// degree: deg[dst] += 1 per edge
// ---------------------------------------------------------------------------
__global__ __launch_bounds__(256) void k_deg(const int* __restrict__ dst,
                                             float* __restrict__ deg, int E) {
    int e = blockIdx.x * 256 + threadIdx.x;
    if (e < E) atomicAdd(deg + dst[e], 1.0f);
}

// ---------------------------------------------------------------------------
// scatter-add: one wave (64 lanes) per edge; lane handles 4 consecutive floats
// summed[dst] += X[src]   (X is [N, 256] fp32)
// ---------------------------------------------------------------------------
__global__ __launch_bounds__(256) void k_scatter(const float* __restrict__ X,
                                                 const int* __restrict__ src,
                                                 const int* __restrict__ dst,
                                                 float* __restrict__ summed, int E) {
    long long gid = (long long)blockIdx.x * 256 + threadIdx.x;
    int e    = (int)(gid >> 6);
    int lane = (int)(gid & 63);
    if (e >= E) return;
    int s = src[e], d = dst[e];
    const float4 v = *reinterpret_cast<const float4*>(X + (size_t)s * D + lane * 4);
    float* o = summed + (size_t)d * D + lane * 4;
    atomicAdd(o + 0, v.x);
    atomicAdd(o + 1, v.y);
    atomicAdd(o + 2, v.z);
    atomicAdd(o + 3, v.w);
}

// ---------------------------------------------------------------------------
// mean: summed[i][:] /= max(deg[i], 1)
// ---------------------------------------------------------------------------
__global__ __launch_bounds__(256) void k_mean(float* __restrict__ summed,
                                              const float* __restrict__ deg, int N) {
    int gid = blockIdx.x * 256 + threadIdx.x;   // one per float4
    int total = N * (D / 4);
    if (gid >= total) return;
    int node = gid / (D / 4);
    float inv = 1.0f / fmaxf(deg[node], 1.0f);
    float4 v = reinterpret_cast<float4*>(summed)[gid];
    v.x *= inv; v.y *= inv; v.z *= inv; v.w *= inv;
    reinterpret_cast<float4*>(summed)[gid] = v;
}

// ---------------------------------------------------------------------------
// fused dual GEMM: C[i][j] = act(bias[j] + A1[i,:]·W1[j,:] + A2[i,:]·W2[j,:])
// A1, A2: [N, 256] row-major; W1, W2: [DOUT, 256] row-major
// tile: BM=64 nodes x BN=64 outputs, BK=32, 256 threads, 4x4 micro-tile
// ---------------------------------------------------------------------------
template <int DOUT, bool RELU>
__global__ __launch_bounds__(256) void k_gemm2(const float* __restrict__ A1,
                                               const float* __restrict__ W1,
                                               const float* __restrict__ A2,
                                               const float* __restrict__ W2,
                                               const float* __restrict__ bias,
                                               float* __restrict__ C, int N) {
    constexpr int BM = 64, BN = 64, BK = 32;
    __shared__ float As[BK][BM + 4];
    __shared__ float Ws[BK][BN + 4];
    int tid = threadIdx.x;
    int tx = tid & 15;    // n (output) dim
    int ty = tid >> 4;    // m (node) dim
    int m0 = blockIdx.x * BM;
    int n0 = blockIdx.y * BN;
    float acc[4][4] = {};

    for (int half = 0; half < 2; ++half) {
        const float* A = half ? A2 : A1;
        const float* W = half ? W2 : W1;
        for (int k0 = 0; k0 < D; k0 += BK) {
            // cooperative tile load: 64 rows x 8 float4 (=32 floats) each matrix
            int r  = tid >> 3;   // 0..31
            int kv = tid & 7;    // which float4 in the row
#pragma unroll
            for (int rr = 0; rr < 2; ++rr) {
                int row = r + rr * 32;
                int gm  = m0 + row;
                float4 v = (gm < N)
                    ? *reinterpret_cast<const float4*>(A + (size_t)gm * D + k0 + kv * 4)
                    : make_float4(0.f, 0.f, 0.f, 0.f);
                As[kv * 4 + 0][row] = v.x;
                As[kv * 4 + 1][row] = v.y;
                As[kv * 4 + 2][row] = v.z;
                As[kv * 4 + 3][row] = v.w;
                int gn = n0 + row;   // DOUT divisible by 64 -> always in bounds
                float4 w = *reinterpret_cast<const float4*>(W + (size_t)gn * D + k0 + kv * 4);
                Ws[kv * 4 + 0][row] = w.x;
                Ws[kv * 4 + 1][row] = w.y;
                Ws[kv * 4 + 2][row] = w.z;
                Ws[kv * 4 + 3][row] = w.w;
            }
            __syncthreads();
#pragma unroll
            for (int k = 0; k < BK; ++k) {
                float4 a = *reinterpret_cast<const float4*>(&As[k][ty * 4]);
                float4 b = *reinterpret_cast<const float4*>(&Ws[k][tx * 4]);
                float av[4] = {a.x, a.y, a.z, a.w};
                float bv[4] = {b.x, b.y, b.z, b.w};
#pragma unroll
                for (int i = 0; i < 4; ++i)
#pragma unroll
                    for (int j = 0; j < 4; ++j) acc[i][j] += av[i] * bv[j];
            }
            __syncthreads();
        }
    }

    // epilogue: bias (+relu), float4 stores
#pragma unroll
    for (int i = 0; i < 4; ++i) {
        int gm = m0 + ty * 4 + i;
        if (gm >= N) continue;
        int gn = n0 + tx * 4;
        float4 v;
        v.x = acc[i][0] + bias[gn + 0];
        v.y = acc[i][1] + bias[gn + 1];
        v.z = acc[i][2] + bias[gn + 2];
        v.w = acc[i][3] + bias[gn + 3];
        if (RELU) {
            v.x = fmaxf(v.x, 0.f); v.y = fmaxf(v.y, 0.f);
            v.z = fmaxf(v.z, 0.f); v.w = fmaxf(v.w, 0.f);
        }
        *reinterpret_cast<float4*>(C + (size_t)gm * DOUT + gn) = v;
    }
}

// ---------------------------------------------------------------------------
extern "C" void kernel_launch(void* const* d_in, const int* in_sizes, int n_in,
                              void* d_out, int out_size, void* d_ws, size_t ws_size,
                              hipStream_t stream) {
    const float* x   = (const float*)d_in[0];
    const int*   ei  = (const int*)d_in[1];
    const float* W1l = (const float*)d_in[2];
    const float* b1  = (const float*)d_in[3];
    const float* W1r = (const float*)d_in[4];
    const float* W2l = (const float*)d_in[5];
    const float* b2  = (const float*)d_in[6];
    const float* W2r = (const float*)d_in[7];
    float* out = (float*)d_out;

    const int N = in_sizes[0] / D;   // 100000
    const int E = in_sizes[1] / 2;   // 1600000
    const int* src = ei;
    const int* dst = ei + E;

    // workspace layout: bufA [N*256] | bufB [N*256] | deg [N]
    float* bufA = (float*)d_ws;
    float* bufB = bufA + (size_t)N * D;
    float* deg  = bufB + (size_t)N * D;

    const size_t featBytes = (size_t)N * D * sizeof(float);
    int scatterBlocks = (int)(((long long)E * 64 + 255) / 256);
    int meanBlocks    = (N * (D / 4) + 255) / 256;
    dim3 gemmGrid1((N + 63) / 64, 256 / 64);
    dim3 gemmGrid2((N + 63) / 64, 128 / 64);

    // ---- degree (shared by both layers) ----
    hipMemsetAsync(deg, 0, (size_t)N * sizeof(float), stream);
    k_deg<<<(E + 255) / 256, 256, 0, stream>>>(dst, deg, E);

    // ---- layer 1: h = relu(mean_agg(x) @ W1l^T + b1 + x @ W1r^T) ----
    hipMemsetAsync(bufA, 0, featBytes, stream);
    k_scatter<<<scatterBlocks, 256, 0, stream>>>(x, src, dst, bufA, E);
    k_mean<<<meanBlocks, 256, 0, stream>>>(bufA, deg, N);
    k_gemm2<256, true><<<gemmGrid1, 256, 0, stream>>>(bufA, W1l, x, W1r, b1, bufB, N);

    // ---- layer 2: out = mean_agg(h) @ W2l^T + b2 + h @ W2r^T ----
    hipMemsetAsync(bufA, 0, featBytes, stream);
    k_scatter<<<scatterBlocks, 256, 0, stream>>>(bufB, src, dst, bufA, E);
    k_mean<<<meanBlocks, 256, 0, stream>>>(bufA, deg, N);
    k_gemm2<128, false><<<gemmGrid2, 256, 0, stream>>>(bufA, W2l, bufB, W2r, b2, out, N);
}

// Round 2
// 1496.963 us; speedup vs baseline: 7.6686x; 7.6686x over previous
//
#include <hip/hip_runtime.h>

#define DK 256   // K dim of every GEMM (D_IN == D_HID == 256)

// ---------------------------------------------------------------------------
// CSR build step 1: integer degree histogram
// ---------------------------------------------------------------------------
__global__ __launch_bounds__(256) void k_deg_i(const int* __restrict__ dst,
                                               int* __restrict__ degi, int E) {
    int e = blockIdx.x * 256 + threadIdx.x;
    if (e < E) atomicAdd(degi + dst[e], 1);
}

// ---------------------------------------------------------------------------
// CSR build step 2: exclusive scan over N degrees (single workgroup, 1024 thr)
// also emits cursor copy and invdeg = 1/max(deg,1)
// ---------------------------------------------------------------------------
__global__ __launch_bounds__(1024) void k_scan(const int* __restrict__ degi,
                                               int* __restrict__ rowptr,
                                               int* __restrict__ cursor,
                                               float* __restrict__ invdeg, int N) {
    __shared__ int part[1024];
    int t = threadIdx.x;
    int chunk = (N + 1023) / 1024;
    int lo = t * chunk;
    int hi = min(lo + chunk, N);
    int s = 0;
    for (int i = lo; i < hi; ++i) s += degi[i];
    part[t] = s;
    __syncthreads();
    // Hillis-Steele inclusive scan of 1024 partials
    for (int off = 1; off < 1024; off <<= 1) {
        int v = (t >= off) ? part[t - off] : 0;
        __syncthreads();
        part[t] += v;
        __syncthreads();
    }
    int run = (t == 0) ? 0 : part[t - 1];   // exclusive prefix of this chunk
    for (int i = lo; i < hi; ++i) {
        rowptr[i] = run;
        cursor[i] = run;
        int d = degi[i];
        invdeg[i] = 1.0f / fmaxf((float)d, 1.0f);
        run += d;
    }
    if (t == 1023) rowptr[N] = part[1023];  // total == E
}

// ---------------------------------------------------------------------------
// CSR build step 3: place src ids into the dst-sorted column array
// (order within a node's list is irrelevant for a sum)
// ---------------------------------------------------------------------------
__global__ __launch_bounds__(256) void k_fill(const int* __restrict__ src,
                                              const int* __restrict__ dst,
                                              int* __restrict__ cursor,
                                              int* __restrict__ col, int E) {
    int e = blockIdx.x * 256 + threadIdx.x;
    if (e < E) {
        int p = atomicAdd(cursor + dst[e], 1);
        col[p] = src[e];
    }
}

// ---------------------------------------------------------------------------
// GEMM: C[m, n0+j] = A[m,:] . W[n0+j,:]   K = 256 fixed
// Weight matrix is segmented: cols [0,DOUTA) from Wa, rest from Wb.
// (n-tile of 64 never straddles the segment boundary since DOUTA % 64 == 0)
// tile: BM=64 x BN=64, BK=32, 256 threads, 4x4 micro-tile. No epilogue math
// (bias/relu live in the aggregation kernel).
// ---------------------------------------------------------------------------
__global__ __launch_bounds__(256) void k_gemm(const float* __restrict__ A, int lda,
                                              const float* __restrict__ Wa, int DOUTA,
                                              const float* __restrict__ Wb,
                                              float* __restrict__ C, int ldc, int N) {
    constexpr int BM = 64, BN = 64, BK = 32;
    __shared__ float As[BK][BM + 4];
    __shared__ float Ws[BK][BN + 4];
    int tid = threadIdx.x;
    int tx = tid & 15;    // n dim
    int ty = tid >> 4;    // m dim
    int m0 = blockIdx.x * BM;
    int n0 = blockIdx.y * BN;
    const float* W = (n0 < DOUTA) ? Wa + (size_t)n0 * DK
                                  : Wb + (size_t)(n0 - DOUTA) * DK;
    float acc[4][4] = {};

    for (int k0 = 0; k0 < DK; k0 += BK) {
        int r  = tid >> 3;   // 0..31
        int kv = tid & 7;    // float4 index within the 32-wide k slice
#pragma unroll
        for (int rr = 0; rr < 2; ++rr) {
            int row = r + rr * 32;
            int gm  = m0 + row;
            float4 v = (gm < N)
                ? *reinterpret_cast<const float4*>(A + (size_t)gm * lda + k0 + kv * 4)
                : make_float4(0.f, 0.f, 0.f, 0.f);
            As[kv * 4 + 0][row] = v.x;
            As[kv * 4 + 1][row] = v.y;
            As[kv * 4 + 2][row] = v.z;
            As[kv * 4 + 3][row] = v.w;
            float4 w = *reinterpret_cast<const float4*>(W + (size_t)row * DK + k0 + kv * 4);
            Ws[kv * 4 + 0][row] = w.x;
            Ws[kv * 4 + 1][row] = w.y;
            Ws[kv * 4 + 2][row] = w.z;
            Ws[kv * 4 + 3][row] = w.w;
        }
        __syncthreads();
#pragma unroll
        for (int k = 0; k < BK; ++k) {
            float4 a = *reinterpret_cast<const float4*>(&As[k][ty * 4]);
            float4 b = *reinterpret_cast<const float4*>(&Ws[k][tx * 4]);
            float av[4] = {a.x, a.y, a.z, a.w};
            float bv[4] = {b.x, b.y, b.z, b.w};
#pragma unroll
            for (int i = 0; i < 4; ++i)
#pragma unroll
                for (int j = 0; j < 4; ++j) acc[i][j] += av[i] * bv[j];
        }
        __syncthreads();
    }

#pragma unroll
    for (int i = 0; i < 4; ++i) {
        int gm = m0 + ty * 4 + i;
        if (gm >= N) continue;
        float4 v = make_float4(acc[i][0], acc[i][1], acc[i][2], acc[i][3]);
        *reinterpret_cast<float4*>(C + (size_t)gm * ldc + n0 + tx * 4) = v;
    }
}

// ---------------------------------------------------------------------------
// gather-aggregate + epilogue: one wave per node.
// O[i] = act( (sum_{j in N(i)} Y[j]) * invdeg[i] + bias + R[i] )
// WID = feature width (256 -> float4/lane, 128 -> float2/lane)
// ---------------------------------------------------------------------------
template <int WID, bool RELU>
__global__ __launch_bounds__(256) void k_agg(const float* __restrict__ Y, int ldy,
                                             const float* __restrict__ R, int ldr,
                                             const float* __restrict__ bias,
                                             const float* __restrict__ invdeg,
                                             const int* __restrict__ rowptr,
                                             const int* __restrict__ col,
                                             float* __restrict__ O, int ldo, int N) {
    constexpr int VEC = WID / 64;            // floats per lane: 4 or 2
    long long g = (long long)blockIdx.x * 256 + threadIdx.x;
    int node = (int)(g >> 6);
    int lane = (int)(g & 63);
    if (node >= N) return;

    int beg = rowptr[node];
    int end = rowptr[node + 1];
    const float* ybase = Y + (size_t)lane * VEC;
    float acc[VEC] = {};

    int e = beg;
    for (; e + 1 < end; e += 2) {            // 2-wide to keep loads in flight
        int s0 = col[e], s1 = col[e + 1];
        if constexpr (VEC == 4) {
            float4 v0 = *reinterpret_cast<const float4*>(ybase + (size_t)s0 * ldy);
            float4 v1 = *reinterpret_cast<const float4*>(ybase + (size_t)s1 * ldy);
            acc[0] += v0.x + v1.x; acc[1] += v0.y + v1.y;
            acc[2] += v0.z + v1.z; acc[3] += v0.w + v1.w;
        } else {
            float2 v0 = *reinterpret_cast<const float2*>(ybase + (size_t)s0 * ldy);
            float2 v1 = *reinterpret_cast<const float2*>(ybase + (size_t)s1 * ldy);
            acc[0] += v0.x + v1.x; acc[1] += v0.y + v1.y;
        }
    }
    if (e < end) {
        int s0 = col[e];
        if constexpr (VEC == 4) {
            float4 v0 = *reinterpret_cast<const float4*>(ybase + (size_t)s0 * ldy);
            acc[0] += v0.x; acc[1] += v0.y; acc[2] += v0.z; acc[3] += v0.w;
        } else {
            float2 v0 = *reinterpret_cast<const float2*>(ybase + (size_t)s0 * ldy);
            acc[0] += v0.x; acc[1] += v0.y;
        }
    }

    float inv = invdeg[node];
    const float* rp = R + (size_t)node * ldr + lane * VEC;
    const float* bp = bias + lane * VEC;
    float* op = O + (size_t)node * ldo + lane * VEC;
    if constexpr (VEC == 4) {
        float4 r = *reinterpret_cast<const float4*>(rp);
        float4 b = *reinterpret_cast<const float4*>(bp);
        float4 o;
        o.x = acc[0] * inv + b.x + r.x;
        o.y = acc[1] * inv + b.y + r.y;
        o.z = acc[2] * inv + b.z + r.z;
        o.w = acc[3] * inv + b.w + r.w;
        if (RELU) {
            o.x = fmaxf(o.x, 0.f); o.y = fmaxf(o.y, 0.f);
            o.z = fmaxf(o.z, 0.f); o.w = fmaxf(o.w, 0.f);
        }
        *reinterpret_cast<float4*>(op) = o;
    } else {
        float2 r = *reinterpret_cast<const float2*>(rp);
        float2 b = *reinterpret_cast<const float2*>(bp);
        float2 o;
        o.x = acc[0] * inv + b.x + r.x;
        o.y = acc[1] * inv + b.y + r.y;
        if (RELU) { o.x = fmaxf(o.x, 0.f); o.y = fmaxf(o.y, 0.f); }
        *reinterpret_cast<float2*>(op) = o;
    }
}

// ---------------------------------------------------------------------------
extern "C" void kernel_launch(void* const* d_in, const int* in_sizes, int n_in,
                              void* d_out, int out_size, void* d_ws, size_t ws_size,
                              hipStream_t stream) {
    const float* x   = (const float*)d_in[0];
    const int*   ei  = (const int*)d_in[1];
    const float* W1l = (const float*)d_in[2];
    const float* b1  = (const float*)d_in[3];
    const float* W1r = (const float*)d_in[4];
    const float* W2l = (const float*)d_in[5];
    const float* b2  = (const float*)d_in[6];
    const float* W2r = (const float*)d_in[7];
    float* out = (float*)d_out;

    const int N = in_sizes[0] / DK;   // 100000
    const int E = in_sizes[1] / 2;    // 1600000
    const int* src = ei;
    const int* dst = ei + E;

    // workspace layout (floats then ints):
    //   buf   [N,512] fp32 : GEMM1 -> y1(cols 0..255) | r1(cols 256..511)
    //                        agg1  -> h overwrites r1 slot (cols 256..511)
    //                        GEMM2 -> y2(cols 0..127) | r2(cols 128..255)
    float* buf    = (float*)d_ws;
    float* invdeg = buf + (size_t)N * 512;
    int*   degi   = (int*)(invdeg + N);
    int*   rowptr = degi + N;            // N+1
    int*   cursor = rowptr + (N + 1);
    int*   col    = cursor + N;          // E

    // ---- CSR build (shared by both layers) ----
    hipMemsetAsync(degi, 0, (size_t)N * sizeof(int), stream);
    k_deg_i<<<(E + 255) / 256, 256, 0, stream>>>(dst, degi, E);
    k_scan<<<1, 1024, 0, stream>>>(degi, rowptr, cursor, invdeg, N);
    k_fill<<<(E + 255) / 256, 256, 0, stream>>>(src, dst, cursor, col, E);

    int mTiles = (N + 63) / 64;
    int aggBlocks = (N + 3) / 4;     // 4 waves (nodes) per 256-thread block

    // ---- layer 1 ----
    // GEMM1: buf[:,0:256] = x@W1l^T ; buf[:,256:512] = x@W1r^T
    k_gemm<<<dim3(mTiles, 8), 256, 0, stream>>>(x, DK, W1l, 256, W1r, buf, 512, N);
    // h = relu(mean_agg(y1) + b1 + r1), written over r1 (cols 256..511)
    k_agg<256, true><<<aggBlocks, 256, 0, stream>>>(
        buf, 512, buf + 256, 512, b1, invdeg, rowptr, col, buf + 256, 512, N);

    // ---- layer 2 ----
    // GEMM2: buf[:,0:128] = h@W2l^T ; buf[:,128:256] = h@W2r^T  (reads cols 256..511)
    k_gemm<<<dim3(mTiles, 4), 256, 0, stream>>>(buf + 256, 512, W2l, 128, W2r, buf, 512, N);
    // out = mean_agg(y2) + b2 + r2
    k_agg<128, false><<<aggBlocks, 256, 0, stream>>>(
        buf, 512, buf + 128, 512, b2, invdeg, rowptr, col, out, 128, N);
}

// Round 3
// 956.273 us; speedup vs baseline: 12.0046x; 1.5654x over previous
//
#include <hip/hip_runtime.h>

#define DK 256   // K dim of every GEMM (D_IN == D_HID == 256)

typedef __attribute__((ext_vector_type(8))) short bf16x8;   // 8 bf16 in 4 VGPRs
typedef __attribute__((ext_vector_type(4))) float f32x4;

__device__ __forceinline__ unsigned short f2b(float f) {    // RNE fp32->bf16
    unsigned u = __builtin_bit_cast(unsigned, f);
    u += 0x7FFFu + ((u >> 16) & 1u);
    return (unsigned short)(u >> 16);
}
__device__ __forceinline__ float b2f(unsigned short s) {
    return __builtin_bit_cast(float, (unsigned)s << 16);
}
__device__ __forceinline__ void gld_lds16(void* lds, const void* g) {
    __builtin_amdgcn_global_load_lds(
        (const __attribute__((address_space(1))) unsigned int*)g,
        (__attribute__((address_space(3))) unsigned int*)lds, 16, 0, 0);
}

// ---------------------------------------------------------------------------
// fp32 -> bf16 conversion, 4 elems/thread
// ---------------------------------------------------------------------------
__global__ __launch_bounds__(256) void k_cvt(const float* __restrict__ src,
                                             unsigned short* __restrict__ dst, int n4) {
    int i = blockIdx.x * 256 + threadIdx.x;
    if (i < n4) {
        float4 v = reinterpret_cast<const float4*>(src)[i];
        ushort4 o = make_ushort4(f2b(v.x), f2b(v.y), f2b(v.z), f2b(v.w));
        reinterpret_cast<ushort4*>(dst)[i] = o;
    }
}

// ---------------------------------------------------------------------------
// CSR build
// ---------------------------------------------------------------------------
__global__ __launch_bounds__(256) void k_deg_i(const int* __restrict__ dst,
                                               int* __restrict__ degi, int E) {
    int e = blockIdx.x * 256 + threadIdx.x;
    if (e < E) atomicAdd(degi + dst[e], 1);
}

__global__ __launch_bounds__(1024) void k_scan(const int* __restrict__ degi,
                                               int* __restrict__ rowptr,
                                               int* __restrict__ cursor,
                                               float* __restrict__ invdeg, int N) {
    __shared__ int part[1024];
    int t = threadIdx.x;
    int chunk = (N + 1023) / 1024;
    int lo = t * chunk;
    int hi = min(lo + chunk, N);
    int s = 0;
    for (int i = lo; i < hi; ++i) s += degi[i];
    part[t] = s;
    __syncthreads();
    for (int off = 1; off < 1024; off <<= 1) {
        int v = (t >= off) ? part[t - off] : 0;
        __syncthreads();
        part[t] += v;
        __syncthreads();
    }
    int run = (t == 0) ? 0 : part[t - 1];
    for (int i = lo; i < hi; ++i) {
        rowptr[i] = run;
        cursor[i] = run;
        int d = degi[i];
        invdeg[i] = 1.0f / fmaxf((float)d, 1.0f);
        run += d;
    }
    if (t == 1023) rowptr[N] = part[1023];
}

__global__ __launch_bounds__(256) void k_fill(const int* __restrict__ src,
                                              const int* __restrict__ dst,
                                              int* __restrict__ cursor,
                                              int* __restrict__ col, int E) {
    int e = blockIdx.x * 256 + threadIdx.x;
    if (e < E) {
        int p = atomicAdd(cursor + dst[e], 1);
        col[p] = src[e];
    }
}

// ---------------------------------------------------------------------------
// bf16 MFMA GEMM (m97 recipe): C[m,n] = A[m,:]·W[n,:], K=256.
// A [N,256] bf16, W [DOUT,256] bf16 (row-major == B^T).
// 128x128 tile, 256 thr = 4 waves (2x2), each wave 4x4 grid of 16x16x32 MFMA.
// Output split: cols [0,DOUTA) -> Y (bf16, ld=DOUTA);
//               cols [DOUTA,2*DOUTA) -> R (bf16 or fp32 per RF32, ld=DOUTA).
// Bias/relu live in the aggregation kernels.
// ---------------------------------------------------------------------------
template <bool RF32>
__global__ __launch_bounds__(256) void k_gemm_bf16(const unsigned short* __restrict__ A,
                                                   const unsigned short* __restrict__ W,
                                                   unsigned short* __restrict__ Y,
                                                   void* __restrict__ Rv,
                                                   int DOUTA, int N) {
    __shared__ unsigned short As[128 * 32];   // [row][k] bf16, unpadded (global_load_lds)
    __shared__ unsigned short Bs[128 * 32];
    const int tid  = threadIdx.x;
    const int lane = tid & 63;
    const int w    = tid >> 6;
    const int wm   = w & 1, wn = w >> 1;
    const int m0   = blockIdx.x * 128;
    const int n0   = blockIdx.y * 128;
    const int lm   = lane & 15, quad = lane >> 4;

    f32x4 acc[4][4];
#pragma unroll
    for (int i = 0; i < 4; ++i)
#pragma unroll
        for (int j = 0; j < 4; ++j) acc[i][j] = (f32x4){0.f, 0.f, 0.f, 0.f};

    // staging geometry: 8 chunks of 16 rows per tile; wave w stages chunks 2w,2w+1
    const int srow  = lane >> 2;        // row within chunk
    const int skoff = (lane & 3) * 8;   // bf16 offset within 32-wide k slice
    const int ca = 2 * w, cb = 2 * w + 1;

    for (int k0 = 0; k0 < DK; k0 += 32) {
        int ra = min(m0 + 16 * ca + srow, N - 1);   // clamp M tail (stores masked)
        int rb = min(m0 + 16 * cb + srow, N - 1);
        gld_lds16(As + ca * 512, A + (size_t)ra * DK + k0 + skoff);
        gld_lds16(As + cb * 512, A + (size_t)rb * DK + k0 + skoff);
        int na = n0 + 16 * ca + srow;               // DOUT multiple of 128 -> in bounds
        int nb = n0 + 16 * cb + srow;
        gld_lds16(Bs + ca * 512, W + (size_t)na * DK + k0 + skoff);
        gld_lds16(Bs + cb * 512, W + (size_t)nb * DK + k0 + skoff);
        __syncthreads();

        bf16x8 af[4], bfr[4];
#pragma unroll
        for (int mt = 0; mt < 4; ++mt)
            af[mt] = *reinterpret_cast<const bf16x8*>(As + (wm * 64 + mt * 16 + lm) * 32 + quad * 8);
#pragma unroll
        for (int nt = 0; nt < 4; ++nt)
            bfr[nt] = *reinterpret_cast<const bf16x8*>(Bs + (wn * 64 + nt * 16 + lm) * 32 + quad * 8);
#pragma unroll
        for (int mt = 0; mt < 4; ++mt)
#pragma unroll
            for (int nt = 0; nt < 4; ++nt)
                acc[mt][nt] = __builtin_amdgcn_mfma_f32_16x16x32_bf16(af[mt], bfr[nt], acc[mt][nt], 0, 0, 0);
        __syncthreads();
    }

    const bool yPart = (n0 < DOUTA);
#pragma unroll
    for (int mt = 0; mt < 4; ++mt) {
#pragma unroll
        for (int nt = 0; nt < 4; ++nt) {
            int gn = n0 + wn * 64 + nt * 16 + lm;
#pragma unroll
            for (int reg = 0; reg < 4; ++reg) {
                int gm = m0 + wm * 64 + mt * 16 + quad * 4 + reg;
                if (gm < N) {
                    float v = acc[mt][nt][reg];
                    if (yPart) {
                        Y[(size_t)gm * DOUTA + gn] = f2b(v);
                    } else if (RF32) {
                        ((float*)Rv)[(size_t)gm * DOUTA + (gn - DOUTA)] = v;
                    } else {
                        ((unsigned short*)Rv)[(size_t)gm * DOUTA + (gn - DOUTA)] = f2b(v);
                    }
                }
            }
        }
    }
}

// ---------------------------------------------------------------------------
// layer-1 aggregate: H = relu(mean(Y[nbrs]) + bias + R), all feature width 256
// one wave per node, lane holds 4 bf16 lanes' worth (8B loads), fp32 accumulate
// ---------------------------------------------------------------------------
__global__ __launch_bounds__(256) void k_agg256(const unsigned short* __restrict__ Y,
                                                const unsigned short* __restrict__ Rb,
                                                const float* __restrict__ bias,
                                                const float* __restrict__ invdeg,
                                                const int* __restrict__ rowptr,
                                                const int* __restrict__ col,
                                                unsigned short* __restrict__ H, int N) {
    long long g = (long long)blockIdx.x * 256 + threadIdx.x;
    int node = (int)(g >> 6);
    int lane = (int)(g & 63);
    if (node >= N) return;
    int beg = rowptr[node], end = rowptr[node + 1];
    const unsigned short* yb = Y + lane * 4;
    float a0 = 0, a1 = 0, a2 = 0, a3 = 0;
    int e = beg;
    for (; e + 1 < end; e += 2) {
        int s0 = col[e], s1 = col[e + 1];
        ushort4 v0 = *reinterpret_cast<const ushort4*>(yb + (size_t)s0 * 256);
        ushort4 v1 = *reinterpret_cast<const ushort4*>(yb + (size_t)s1 * 256);
        a0 += b2f(v0.x) + b2f(v1.x);
        a1 += b2f(v0.y) + b2f(v1.y);
        a2 += b2f(v0.z) + b2f(v1.z);
        a3 += b2f(v0.w) + b2f(v1.w);
    }
    if (e < end) {
        ushort4 v0 = *reinterpret_cast<const ushort4*>(yb + (size_t)col[e] * 256);
        a0 += b2f(v0.x); a1 += b2f(v0.y); a2 += b2f(v0.z); a3 += b2f(v0.w);
    }
    float inv = invdeg[node];
    int c = lane * 4;
    ushort4 r = *reinterpret_cast<const ushort4*>(Rb + (size_t)node * 256 + c);
    float o0 = fmaxf(a0 * inv + bias[c + 0] + b2f(r.x), 0.f);
    float o1 = fmaxf(a1 * inv + bias[c + 1] + b2f(r.y), 0.f);
    float o2 = fmaxf(a2 * inv + bias[c + 2] + b2f(r.z), 0.f);
    float o3 = fmaxf(a3 * inv + bias[c + 3] + b2f(r.w), 0.f);
    *reinterpret_cast<ushort4*>(H + (size_t)node * 256 + c) =
        make_ushort4(f2b(o0), f2b(o1), f2b(o2), f2b(o3));
}

// ---------------------------------------------------------------------------
// layer-2 aggregate: O = mean(Y[nbrs]) + bias + R, width 128, fp32 out
// ---------------------------------------------------------------------------
__global__ __launch_bounds__(256) void k_agg128(const unsigned short* __restrict__ Y,
                                                const float* __restrict__ Rf,
                                                const float* __restrict__ bias,
                                                const float* __restrict__ invdeg,
                                                const int* __restrict__ rowptr,
                                                const int* __restrict__ col,
                                                float* __restrict__ O, int N) {
    long long g = (long long)blockIdx.x * 256 + threadIdx.x;
    int node = (int)(g >> 6);
    int lane = (int)(g & 63);
    if (node >= N) return;
    int beg = rowptr[node], end = rowptr[node + 1];
    const unsigned short* yb = Y + lane * 2;
    float a0 = 0, a1 = 0;
    int e = beg;
    for (; e + 1 < end; e += 2) {
        int s0 = col[e], s1 = col[e + 1];
        unsigned v0 = *reinterpret_cast<const unsigned*>(yb + (size_t)s0 * 128);
        unsigned v1 = *reinterpret_cast<const unsigned*>(yb + (size_t)s1 * 128);
        a0 += b2f((unsigned short)(v0 & 0xffff)) + b2f((unsigned short)(v1 & 0xffff));
        a1 += b2f((unsigned short)(v0 >> 16)) + b2f((unsigned short)(v1 >> 16));
    }
    if (e < end) {
        unsigned v0 = *reinterpret_cast<const unsigned*>(yb + (size_t)col[e] * 128);
        a0 += b2f((unsigned short)(v0 & 0xffff));
        a1 += b2f((unsigned short)(v0 >> 16));
    }
    float inv = invdeg[node];
    int c = lane * 2;
    float2 r = *reinterpret_cast<const float2*>(Rf + (size_t)node * 128 + c);
    float2 o;
    o.x = a0 * inv + bias[c + 0] + r.x;
    o.y = a1 * inv + bias[c + 1] + r.y;
    *reinterpret_cast<float2*>(O + (size_t)node * 128 + c) = o;
}

// ---------------------------------------------------------------------------
extern "C" void kernel_launch(void* const* d_in, const int* in_sizes, int n_in,
                              void* d_out, int out_size, void* d_ws, size_t ws_size,
                              hipStream_t stream) {
    const float* x   = (const float*)d_in[0];
    const int*   ei  = (const int*)d_in[1];
    const float* W1l = (const float*)d_in[2];
    const float* b1  = (const float*)d_in[3];
    const float* W1r = (const float*)d_in[4];
    const float* W2l = (const float*)d_in[5];
    const float* b2  = (const float*)d_in[6];
    const float* W2r = (const float*)d_in[7];
    float* out = (float*)d_out;

    const int N = in_sizes[0] / DK;   // 100000
    const int E = in_sizes[1] / 2;    // 1600000
    const int* src = ei;
    const int* dst = ei + E;

    // workspace (bf16 regions are N*256 elems = 51.2 MB each):
    //   xb | y1b (y2b aliases) | r1b (r2f fp32[N,128] aliases, same bytes) | hb
    //   Wb1[512*256] Wb2[256*256] | invdeg | degi | rowptr | cursor | col
    unsigned short* xb  = (unsigned short*)d_ws;
    unsigned short* y1b = xb + (size_t)N * 256;
    unsigned short* r1b = y1b + (size_t)N * 256;
    unsigned short* hb  = r1b + (size_t)N * 256;
    unsigned short* Wb1 = hb + (size_t)N * 256;
    unsigned short* Wb2 = Wb1 + 512 * 256;
    float* invdeg = (float*)(Wb2 + 256 * 256);
    int* degi   = (int*)(invdeg + N);
    int* rowptr = degi + N;
    int* cursor = rowptr + (N + 1);
    int* col    = cursor + N;
    unsigned short* y2b = y1b;          // layer-2 aliases (lifetimes disjoint)
    float* r2f = (float*)r1b;

    // ---- conversions to bf16 ----
    k_cvt<<<(N * 64 + 255) / 256, 256, 0, stream>>>(x, xb, N * 64);
    k_cvt<<<(16384 + 255) / 256, 256, 0, stream>>>(W1l, Wb1, 16384);
    k_cvt<<<(16384 + 255) / 256, 256, 0, stream>>>(W1r, Wb1 + 256 * 256, 16384);
    k_cvt<<<(8192 + 255) / 256, 256, 0, stream>>>(W2l, Wb2, 8192);
    k_cvt<<<(8192 + 255) / 256, 256, 0, stream>>>(W2r, Wb2 + 128 * 256, 8192);

    // ---- CSR build ----
    hipMemsetAsync(degi, 0, (size_t)N * sizeof(int), stream);
    k_deg_i<<<(E + 255) / 256, 256, 0, stream>>>(dst, degi, E);
    k_scan<<<1, 1024, 0, stream>>>(degi, rowptr, cursor, invdeg, N);
    k_fill<<<(E + 255) / 256, 256, 0, stream>>>(src, dst, cursor, col, E);

    int mTiles = (N + 127) / 128;       // 782
    int aggBlocks = (N + 3) / 4;        // 4 nodes (waves) per block

    // ---- layer 1 ----
    k_gemm_bf16<false><<<dim3(mTiles, 4), 256, 0, stream>>>(xb, Wb1, y1b, r1b, 256, N);
    k_agg256<<<aggBlocks, 256, 0, stream>>>(y1b, r1b, b1, invdeg, rowptr, col, hb, N);

    // ---- layer 2 ----
    k_gemm_bf16<true><<<dim3(mTiles, 2), 256, 0, stream>>>(hb, Wb2, y2b, r2f, 128, N);
    k_agg128<<<aggBlocks, 256, 0, stream>>>(y2b, r2f, b2, invdeg, rowptr, col, out, N);
}

// Round 4
// 690.493 us; speedup vs baseline: 16.6253x; 1.3849x over previous
//
#include <hip/hip_runtime.h>

#define DK 256   // K dim of every GEMM (D_IN == D_HID == 256)

typedef __attribute__((ext_vector_type(8))) short bf16x8;   // 8 bf16 in 4 VGPRs
typedef __attribute__((ext_vector_type(4))) float f32x4;

__device__ __forceinline__ unsigned short f2b(float f) {    // RNE fp32->bf16
    unsigned u = __builtin_bit_cast(unsigned, f);
    u += 0x7FFFu + ((u >> 16) & 1u);
    return (unsigned short)(u >> 16);
}
__device__ __forceinline__ float b2f(unsigned short s) {
    return __builtin_bit_cast(float, (unsigned)s << 16);
}
__device__ __forceinline__ void gld_lds16(void* lds, const void* g) {
    __builtin_amdgcn_global_load_lds(
        (const __attribute__((address_space(1))) unsigned int*)g,
        (__attribute__((address_space(3))) unsigned int*)lds, 16, 0, 0);
}

// ---------------------------------------------------------------------------
// fp32 -> bf16 conversion, 4 elems/thread
// ---------------------------------------------------------------------------
__global__ __launch_bounds__(256) void k_cvt(const float* __restrict__ src,
                                             unsigned short* __restrict__ dst, int n4) {
    int i = blockIdx.x * 256 + threadIdx.x;
    if (i < n4) {
        float4 v = reinterpret_cast<const float4*>(src)[i];
        ushort4 o = make_ushort4(f2b(v.x), f2b(v.y), f2b(v.z), f2b(v.w));
        reinterpret_cast<ushort4*>(dst)[i] = o;
    }
}

// ---------------------------------------------------------------------------
// CSR build
// ---------------------------------------------------------------------------
__global__ __launch_bounds__(256) void k_deg_i(const int* __restrict__ dst,
                                               int* __restrict__ degi, int E) {
    int e = blockIdx.x * 256 + threadIdx.x;
    if (e < E) atomicAdd(degi + dst[e], 1);
}

// device-wide exclusive scan over degi (3 kernels, 1024 elems/block)
__global__ __launch_bounds__(256) void k_scan_a(const int* __restrict__ degi,
                                                int* __restrict__ bsum, int N) {
    __shared__ int sm[256];
    int t = threadIdx.x;
    int i0 = blockIdx.x * 1024 + t * 4;
    int s = 0;
    if (i0 + 3 < N) {
        int4 v = *reinterpret_cast<const int4*>(degi + i0);
        s = v.x + v.y + v.z + v.w;
    } else {
        for (int i = i0; i < min(i0 + 4, N); ++i) s += degi[i];
    }
    sm[t] = s;
    __syncthreads();
    for (int off = 128; off > 0; off >>= 1) {
        if (t < off) sm[t] += sm[t + off];
        __syncthreads();
    }
    if (t == 0) bsum[blockIdx.x] = sm[0];
}

__global__ __launch_bounds__(256) void k_scan_b(const int* __restrict__ bsum,
                                                int* __restrict__ boff,
                                                int* __restrict__ rowptrN, int NB) {
    __shared__ int sm[256];
    int t = threadIdx.x;
    sm[t] = (t < NB) ? bsum[t] : 0;
    __syncthreads();
    for (int off = 1; off < 256; off <<= 1) {
        int v = (t >= off) ? sm[t - off] : 0;
        __syncthreads();
        sm[t] += v;
        __syncthreads();
    }
    if (t < NB) boff[t] = (t == 0) ? 0 : sm[t - 1];
    if (t == NB - 1) *rowptrN = sm[t];
}

__global__ __launch_bounds__(256) void k_scan_c(const int* __restrict__ degi,
                                                const int* __restrict__ boff,
                                                int* __restrict__ rowptr,
                                                int* __restrict__ cursor,
                                                float* __restrict__ invdeg, int N) {
    __shared__ int sm[256];
    int t = threadIdx.x;
    int i0 = blockIdx.x * 1024 + t * 4;
    int d0 = 0, d1 = 0, d2 = 0, d3 = 0;
    if (i0 + 3 < N) {
        int4 v = *reinterpret_cast<const int4*>(degi + i0);
        d0 = v.x; d1 = v.y; d2 = v.z; d3 = v.w;
    } else {
        if (i0 + 0 < N) d0 = degi[i0 + 0];
        if (i0 + 1 < N) d1 = degi[i0 + 1];
        if (i0 + 2 < N) d2 = degi[i0 + 2];
        if (i0 + 3 < N) d3 = degi[i0 + 3];
    }
    int s = d0 + d1 + d2 + d3;
    sm[t] = s;
    __syncthreads();
    for (int off = 1; off < 256; off <<= 1) {
        int v = (t >= off) ? sm[t - off] : 0;
        __syncthreads();
        sm[t] += v;
        __syncthreads();
    }
    int run = boff[blockIdx.x] + sm[t] - s;    // exclusive prefix of this thread
    int dd[4] = {d0, d1, d2, d3};
#pragma unroll
    for (int i = 0; i < 4; ++i) {
        int idx = i0 + i;
        if (idx < N) {
            rowptr[idx] = run;
            cursor[idx] = run;
            invdeg[idx] = 1.0f / fmaxf((float)dd[i], 1.0f);
            run += dd[i];
        }
    }
}

__global__ __launch_bounds__(256) void k_fill(const int* __restrict__ src,
                                              const int* __restrict__ dst,
                                              int* __restrict__ cursor,
                                              int* __restrict__ col, int E) {
    int e = blockIdx.x * 256 + threadIdx.x;
    if (e < E) {
        int p = atomicAdd(cursor + dst[e], 1);
        col[p] = src[e];
    }
}

// ---------------------------------------------------------------------------
// bf16 MFMA GEMM (m97 recipe): C[m,n] = A[m,:]·W[n,:], K=256.
// A [N,256] bf16, W [DOUT,256] bf16 (row-major == B^T).
// 128x128 tile, 256 thr = 4 waves (2x2), each wave 4x4 grid of 16x16x32 MFMA.
// Output split: cols [0,DOUTA) -> Y (bf16, ld=DOUTA);
//               cols [DOUTA,2*DOUTA) -> R (bf16 or fp32 per RF32, ld=DOUTA).
// Bias/relu live in the aggregation kernels.
// ---------------------------------------------------------------------------
template <bool RF32>
__global__ __launch_bounds__(256) void k_gemm_bf16(const unsigned short* __restrict__ A,
                                                   const unsigned short* __restrict__ W,
                                                   unsigned short* __restrict__ Y,
                                                   void* __restrict__ Rv,
                                                   int DOUTA, int N) {
    __shared__ unsigned short As[128 * 32];   // [row][k] bf16, unpadded (global_load_lds)
    __shared__ unsigned short Bs[128 * 32];
    const int tid  = threadIdx.x;
    const int lane = tid & 63;
    const int w    = tid >> 6;
    const int wm   = w & 1, wn = w >> 1;
    const int m0   = blockIdx.x * 128;
    const int n0   = blockIdx.y * 128;
    const int lm   = lane & 15, quad = lane >> 4;

    f32x4 acc[4][4];
#pragma unroll
    for (int i = 0; i < 4; ++i)
#pragma unroll
        for (int j = 0; j < 4; ++j) acc[i][j] = (f32x4){0.f, 0.f, 0.f, 0.f};

    // staging geometry: 8 chunks of 16 rows per tile; wave w stages chunks 2w,2w+1
    const int srow  = lane >> 2;        // row within chunk
    const int skoff = (lane & 3) * 8;   // bf16 offset within 32-wide k slice
    const int ca = 2 * w, cb = 2 * w + 1;

    for (int k0 = 0; k0 < DK; k0 += 32) {
        int ra = min(m0 + 16 * ca + srow, N - 1);   // clamp M tail (stores masked)
        int rb = min(m0 + 16 * cb + srow, N - 1);
        gld_lds16(As + ca * 512, A + (size_t)ra * DK + k0 + skoff);
        gld_lds16(As + cb * 512, A + (size_t)rb * DK + k0 + skoff);
        int na = n0 + 16 * ca + srow;               // DOUT multiple of 128 -> in bounds
        int nb = n0 + 16 * cb + srow;
        gld_lds16(Bs + ca * 512, W + (size_t)na * DK + k0 + skoff);
        gld_lds16(Bs + cb * 512, W + (size_t)nb * DK + k0 + skoff);
        __syncthreads();

        bf16x8 af[4], bfr[4];
#pragma unroll
        for (int mt = 0; mt < 4; ++mt)
            af[mt] = *reinterpret_cast<const bf16x8*>(As + (wm * 64 + mt * 16 + lm) * 32 + quad * 8);
#pragma unroll
        for (int nt = 0; nt < 4; ++nt)
            bfr[nt] = *reinterpret_cast<const bf16x8*>(Bs + (wn * 64 + nt * 16 + lm) * 32 + quad * 8);
#pragma unroll
        for (int mt = 0; mt < 4; ++mt)
#pragma unroll
            for (int nt = 0; nt < 4; ++nt)
                acc[mt][nt] = __builtin_amdgcn_mfma_f32_16x16x32_bf16(af[mt], bfr[nt], acc[mt][nt], 0, 0, 0);
        __syncthreads();
    }

    const bool yPart = (n0 < DOUTA);
#pragma unroll
    for (int mt = 0; mt < 4; ++mt) {
#pragma unroll
        for (int nt = 0; nt < 4; ++nt) {
            int gn = n0 + wn * 64 + nt * 16 + lm;
#pragma unroll
            for (int reg = 0; reg < 4; ++reg) {
                int gm = m0 + wm * 64 + mt * 16 + quad * 4 + reg;
                if (gm < N) {
                    float v = acc[mt][nt][reg];
                    if (yPart) {
                        Y[(size_t)gm * DOUTA + gn] = f2b(v);
                    } else if (RF32) {
                        ((float*)Rv)[(size_t)gm * DOUTA + (gn - DOUTA)] = v;
                    } else {
                        ((unsigned short*)Rv)[(size_t)gm * DOUTA + (gn - DOUTA)] = f2b(v);
                    }
                }
            }
        }
    }
}

// ---------------------------------------------------------------------------
// layer-1 aggregate: H = relu(mean(Y[nbrs]) + bias + R), all feature width 256
// one wave per node, lane holds 4 bf16 lanes' worth (8B loads), fp32 accumulate
// ---------------------------------------------------------------------------
__global__ __launch_bounds__(256) void k_agg256(const unsigned short* __restrict__ Y,
                                                const unsigned short* __restrict__ Rb,
                                                const float* __restrict__ bias,
                                                const float* __restrict__ invdeg,
                                                const int* __restrict__ rowptr,
                                                const int* __restrict__ col,
                                                unsigned short* __restrict__ H, int N) {
    long long g = (long long)blockIdx.x * 256 + threadIdx.x;
    int node = (int)(g >> 6);
    int lane = (int)(g & 63);
    if (node >= N) return;
    int beg = rowptr[node], end = rowptr[node + 1];
    const unsigned short* yb = Y + lane * 4;
    float a0 = 0, a1 = 0, a2 = 0, a3 = 0;
    int e = beg;
    for (; e + 1 < end; e += 2) {
        int s0 = col[e], s1 = col[e + 1];
        ushort4 v0 = *reinterpret_cast<const ushort4*>(yb + (size_t)s0 * 256);
        ushort4 v1 = *reinterpret_cast<const ushort4*>(yb + (size_t)s1 * 256);
        a0 += b2f(v0.x) + b2f(v1.x);
        a1 += b2f(v0.y) + b2f(v1.y);
        a2 += b2f(v0.z) + b2f(v1.z);
        a3 += b2f(v0.w) + b2f(v1.w);
    }
    if (e < end) {
        ushort4 v0 = *reinterpret_cast<const ushort4*>(yb + (size_t)col[e] * 256);
        a0 += b2f(v0.x); a1 += b2f(v0.y); a2 += b2f(v0.z); a3 += b2f(v0.w);
    }
    float inv = invdeg[node];
    int c = lane * 4;
    ushort4 r = *reinterpret_cast<const ushort4*>(Rb + (size_t)node * 256 + c);
    float o0 = fmaxf(a0 * inv + bias[c + 0] + b2f(r.x), 0.f);
    float o1 = fmaxf(a1 * inv + bias[c + 1] + b2f(r.y), 0.f);
    float o2 = fmaxf(a2 * inv + bias[c + 2] + b2f(r.z), 0.f);
    float o3 = fmaxf(a3 * inv + bias[c + 3] + b2f(r.w), 0.f);
    *reinterpret_cast<ushort4*>(H + (size_t)node * 256 + c) =
        make_ushort4(f2b(o0), f2b(o1), f2b(o2), f2b(o3));
}

// ---------------------------------------------------------------------------
// layer-2 aggregate: O = mean(Y[nbrs]) + bias + R, width 128, fp32 out
// ---------------------------------------------------------------------------
__global__ __launch_bounds__(256) void k_agg128(const unsigned short* __restrict__ Y,
                                                const float* __restrict__ Rf,
                                                const float* __restrict__ bias,
                                                const float* __restrict__ invdeg,
                                                const int* __restrict__ rowptr,
                                                const int* __restrict__ col,
                                                float* __restrict__ O, int N) {
    long long g = (long long)blockIdx.x * 256 + threadIdx.x;
    int node = (int)(g >> 6);
    int lane = (int)(g & 63);
    if (node >= N) return;
    int beg = rowptr[node], end = rowptr[node + 1];
    const unsigned short* yb = Y + lane * 2;
    float a0 = 0, a1 = 0;
    int e = beg;
    for (; e + 1 < end; e += 2) {
        int s0 = col[e], s1 = col[e + 1];
        unsigned v0 = *reinterpret_cast<const unsigned*>(yb + (size_t)s0 * 128);
        unsigned v1 = *reinterpret_cast<const unsigned*>(yb + (size_t)s1 * 128);
        a0 += b2f((unsigned short)(v0 & 0xffff)) + b2f((unsigned short)(v1 & 0xffff));
        a1 += b2f((unsigned short)(v0 >> 16)) + b2f((unsigned short)(v1 >> 16));
    }
    if (e < end) {
        unsigned v0 = *reinterpret_cast<const unsigned*>(yb + (size_t)col[e] * 128);
        a0 += b2f((unsigned short)(v0 & 0xffff));
        a1 += b2f((unsigned short)(v0 >> 16));
    }
    float inv = invdeg[node];
    int c = lane * 2;
    float2 r = *reinterpret_cast<const float2*>(Rf + (size_t)node * 128 + c);
    float2 o;
    o.x = a0 * inv + bias[c + 0] + r.x;
    o.y = a1 * inv + bias[c + 1] + r.y;
    *reinterpret_cast<float2*>(O + (size_t)node * 128 + c) = o;
}

// ---------------------------------------------------------------------------
extern "C" void kernel_launch(void* const* d_in, const int* in_sizes, int n_in,
                              void* d_out, int out_size, void* d_ws, size_t ws_size,
                              hipStream_t stream) {
    const float* x   = (const float*)d_in[0];
    const int*   ei  = (const int*)d_in[1];
    const float* W1l = (const float*)d_in[2];
    const float* b1  = (const float*)d_in[3];
    const float* W1r = (const float*)d_in[4];
    const float* W2l = (const float*)d_in[5];
    const float* b2  = (const float*)d_in[6];
    const float* W2r = (const float*)d_in[7];
    float* out = (float*)d_out;

    const int N = in_sizes[0] / DK;   // 100000
    const int E = in_sizes[1] / 2;    // 1600000
    const int* src = ei;
    const int* dst = ei + E;

    // workspace (bf16 regions are N*256 elems = 51.2 MB each):
    //   xb | y1b (y2b aliases) | r1b (r2f fp32[N,128] aliases, same bytes) | hb
    //   Wb1[512*256] Wb2[256*256] | invdeg | degi | rowptr | cursor | col | bsum | boff
    unsigned short* xb  = (unsigned short*)d_ws;
    unsigned short* y1b = xb + (size_t)N * 256;
    unsigned short* r1b = y1b + (size_t)N * 256;
    unsigned short* hb  = r1b + (size_t)N * 256;
    unsigned short* Wb1 = hb + (size_t)N * 256;
    unsigned short* Wb2 = Wb1 + 512 * 256;
    float* invdeg = (float*)(Wb2 + 256 * 256);
    int* degi   = (int*)(invdeg + N);
    int* rowptr = degi + N;
    int* cursor = rowptr + (N + 1);
    int* col    = cursor + N;
    int* bsum   = col + E;
    int* boff   = bsum + 512;
    unsigned short* y2b = y1b;          // layer-2 aliases (lifetimes disjoint)
    float* r2f = (float*)r1b;

    // ---- conversions to bf16 ----
    k_cvt<<<(N * 64 + 255) / 256, 256, 0, stream>>>(x, xb, N * 64);
    k_cvt<<<(16384 + 255) / 256, 256, 0, stream>>>(W1l, Wb1, 16384);
    k_cvt<<<(16384 + 255) / 256, 256, 0, stream>>>(W1r, Wb1 + 256 * 256, 16384);
    k_cvt<<<(8192 + 255) / 256, 256, 0, stream>>>(W2l, Wb2, 8192);
    k_cvt<<<(8192 + 255) / 256, 256, 0, stream>>>(W2r, Wb2 + 128 * 256, 8192);

    // ---- CSR build ----
    const int NB = (N + 1023) / 1024;   // 98 scan blocks
    hipMemsetAsync(degi, 0, (size_t)N * sizeof(int), stream);
    k_deg_i<<<(E + 255) / 256, 256, 0, stream>>>(dst, degi, E);
    k_scan_a<<<NB, 256, 0, stream>>>(degi, bsum, N);
    k_scan_b<<<1, 256, 0, stream>>>(bsum, boff, rowptr + N, NB);
    k_scan_c<<<NB, 256, 0, stream>>>(degi, boff, rowptr, cursor, invdeg, N);
    k_fill<<<(E + 255) / 256, 256, 0, stream>>>(src, dst, cursor, col, E);

    int mTiles = (N + 127) / 128;       // 782
    int aggBlocks = (N + 3) / 4;        // 4 nodes (waves) per block

    // ---- layer 1 ----
    k_gemm_bf16<false><<<dim3(mTiles, 4), 256, 0, stream>>>(xb, Wb1, y1b, r1b, 256, N);
    k_agg256<<<aggBlocks, 256, 0, stream>>>(y1b, r1b, b1, invdeg, rowptr, col, hb, N);

    // ---- layer 2 ----
    k_gemm_bf16<true><<<dim3(mTiles, 2), 256, 0, stream>>>(hb, Wb2, y2b, r2f, 128, N);
    k_agg128<<<aggBlocks, 256, 0, stream>>>(y2b, r2f, b2, invdeg, rowptr, col, out, N);
}